// Round 7
// baseline (1101.406 us; speedup 1.0000x reference)
//
// Round 7: identical resubmission (6th acquisition timeout; the r4 batch
// int64->int32 fix has never executed — it remains the pending experiment).
// Audits to date: dbuf/barrier ordering, LDS banks (xs/hs ≡4-bank rows, wsl
// XOR-uniform), 16B alignment of all vector accesses, tail clamps + guarded
// stores, ws fully rewritten per launch, launch-bounds/graph-capture clean.
// Contingency if absmax fails: +residual (x_lo@W_hi) pass, ~2x MFMA, still
// under the 184 µs HBM floor. Roofline: 1.16 GB -> 184 µs; MFMA 66 µs.
#include <hip/hip_runtime.h>
#include <hip/hip_bf16.h>

#define E_EDGES 500000
#define V_IN 128
#define E_IN 64
#define U_IN 64
#define NG 512
#define HID 256
#define CAT 384          // 2*V_IN + E_IN + U_IN
#define BM 128
#define NCHUNK1 6        // 384/64
#define NCHUNK2 4        // 256/64

typedef short short8 __attribute__((ext_vector_type(8)));
typedef float f32x4 __attribute__((ext_vector_type(4)));

// fp32 -> bf16 round-to-nearest-even
static __device__ __forceinline__ short f2bf(float f) {
  unsigned u = __builtin_bit_cast(unsigned, f);
  u += 0x7fffu + ((u >> 16) & 1u);
  return (short)(u >> 16);
}

static __device__ __forceinline__ void gload_lds16(const void* g, void* l) {
  __builtin_amdgcn_global_load_lds(
      (const __attribute__((address_space(1))) unsigned int*)g,
      (unsigned int __attribute__((address_space(3)))*)l, 16, 0, 0);
}

// Each wave DMAs 4 KB; 8 waves cover the 32 KB tile. LDS dest wave-uniform,
// global src per-lane (rule #21: swizzle baked into SOURCE layout by prep).
static __device__ __forceinline__ void stage_w(const short* gsrc, short* lbase,
                                               int w, int l) {
#pragma unroll
  for (int i = 0; i < 4; ++i) {
    int off = (w * 4 + i) * 1024;
    gload_lds16((const char*)gsrc + off + l * 16, (char*)lbase + off);
  }
}

// Convert W1/W2 to bf16, transposed to [n][k], k-block XOR-swizzled (T2) so
// the main kernel stages linearly and applies the same XOR on the LDS read.
__global__ void prep_weights(const float* __restrict__ W1,
                             const float* __restrict__ W2,
                             short* __restrict__ w1t, short* __restrict__ w2t) {
  int idx = blockIdx.x * 256 + threadIdx.x;
  if (idx < CAT * HID) {
    int kc = idx >> 14;            // tile (64 k x 256 n)
    int rem = idx & 16383;
    int n = rem >> 6, kk = rem & 63;
    int swz = ((((kk >> 3) ^ (n & 7)) << 3) | (kk & 7));
    w1t[kc * 16384 + n * 64 + swz] = f2bf(W1[(size_t)(kc * 64 + kk) * HID + n]);
  } else if (idx < CAT * HID + HID * HID) {
    int j = idx - CAT * HID;
    int kc = j >> 14;
    int rem = j & 16383;
    int n = rem >> 6, kk = rem & 63;
    int swz = ((((kk >> 3) ^ (n & 7)) << 3) | (kk & 7));
    w2t[kc * 16384 + n * 64 + swz] = f2bf(W2[(size_t)(kc * 64 + kk) * HID + n]);
  }
}

__global__ __launch_bounds__(512, 2) void edge_mlp(
    const float* __restrict__ src, const float* __restrict__ dst,
    const float* __restrict__ edg, const float* __restrict__ u,
    const int* __restrict__ batch,
    const float* __restrict__ b1, const float* __restrict__ b2,
    const short* __restrict__ w1t, const short* __restrict__ w2t,
    float* __restrict__ out) {
  // LDS: 18432 + 2*32768 + 67584 + 2048 = 153600 B <= 160 KiB -> 1 block/CU
  __shared__ short xs[BM][72];        // x chunk, bf16, +8 pad (row ≡ 4 banks)
  __shared__ short wsl[2][256 * 64];  // W tile double-buffer, baked swizzle
  __shared__ short hs[BM][264];       // h, bf16, +8 pad (row ≡ 4 banks)
  __shared__ float biasLds[2 * HID];

  const int t = threadIdx.x;
  const int l = t & 63;
  const int w = t >> 6;               // wave 0..7
  const int wr = w >> 2, wc = w & 3;  // wave grid 2x4, wave tile 64x64
  const int l15 = l & 15, lg = l >> 4;
  const int r0 = blockIdx.x * BM;

  // ---- prologue: kick W1(0) DMA immediately, then x(0) loads ----
  stage_w(w1t, wsl[0], w, l);

  const int srow = t >> 2;            // x-staging: row = t/4, 16-col quarter
  const int cq = (t & 3) << 4;
  int gr = r0 + srow;
  if (gr >= E_EDGES) gr = E_EDGES - 1;          // tail clamp (stores guarded)
  int bi = batch[gr];                           // int32 per harness contract
  bi = bi < 0 ? 0 : (bi >= NG ? NG - 1 : bi);   // defensive clamp
  const float* uptr = u + (size_t)bi * U_IN;
  const float* csrc[NCHUNK1] = {
      src + (size_t)gr * V_IN + cq,       src + (size_t)gr * V_IN + 64 + cq,
      dst + (size_t)gr * V_IN + cq,       dst + (size_t)gr * V_IN + 64 + cq,
      edg + (size_t)gr * E_IN + cq,       uptr + cq};

  f32x4 xv0, xv1, xv2, xv3;
  {
    const f32x4* p = (const f32x4*)csrc[0];
    xv0 = p[0]; xv1 = p[1]; xv2 = p[2]; xv3 = p[3];
  }

  if (t < HID) biasLds[t] = b1[t];
  else if (t < 2 * HID) biasLds[t] = b2[t - HID];

  f32x4 acc[4][4];
#pragma unroll
  for (int m = 0; m < 4; ++m)
#pragma unroll
    for (int n = 0; n < 4; ++n)
#pragma unroll
      for (int j = 0; j < 4; ++j) acc[m][n][j] = 0.f;

  // ---------------- layer 1: h = relu(x @ W1 + b1) ----------------
#pragma unroll
  for (int kc = 0; kc < NCHUNK1; ++kc) {
    // write current x chunk (bf16) to LDS
    {
      short8 lo, hi;
      lo[0] = f2bf(xv0[0]); lo[1] = f2bf(xv0[1]); lo[2] = f2bf(xv0[2]); lo[3] = f2bf(xv0[3]);
      lo[4] = f2bf(xv1[0]); lo[5] = f2bf(xv1[1]); lo[6] = f2bf(xv1[2]); lo[7] = f2bf(xv1[3]);
      hi[0] = f2bf(xv2[0]); hi[1] = f2bf(xv2[1]); hi[2] = f2bf(xv2[2]); hi[3] = f2bf(xv2[3]);
      hi[4] = f2bf(xv3[0]); hi[5] = f2bf(xv3[1]); hi[6] = f2bf(xv3[2]); hi[7] = f2bf(xv3[3]);
      *(short8*)&xs[srow][cq] = lo;
      *(short8*)&xs[srow][cq + 8] = hi;
    }
    __syncthreads();  // barrier1: xs ready; W(kc) DMA drained

    // T14 depth-1: issue next W DMA + next x loads; drain overlaps MFMA below
    f32x4 nx0, nx1, nx2, nx3;
    if (kc < NCHUNK1 - 1) {
      stage_w(w1t + (kc + 1) * 16384, wsl[(kc + 1) & 1], w, l);
      const f32x4* p = (const f32x4*)csrc[kc + 1];
      nx0 = p[0]; nx1 = p[1]; nx2 = p[2]; nx3 = p[3];
    } else {
      stage_w(w2t, wsl[0], w, l);  // W2(0) for layer 2 (buf parity: 6 even)
    }

    const short* wcur = wsl[kc & 1];
#pragma unroll
    for (int ks = 0; ks < 2; ++ks) {
      const int k8 = ks * 32 + lg * 8;
      short8 a[4], b[4];
#pragma unroll
      for (int m = 0; m < 4; ++m)
        a[m] = *(const short8*)&xs[wr * 64 + m * 16 + l15][k8];
#pragma unroll
      for (int n = 0; n < 4; ++n) {
        int nn = wc * 64 + n * 16 + l15;
        int blk = (k8 >> 3) ^ (nn & 7);
        b[n] = *(const short8*)&wcur[nn * 64 + blk * 8];
      }
#pragma unroll
      for (int m = 0; m < 4; ++m)
#pragma unroll
        for (int n = 0; n < 4; ++n)
          acc[m][n] = __builtin_amdgcn_mfma_f32_16x16x32_bf16(a[m], b[n], acc[m][n], 0, 0, 0);
    }
    __syncthreads();  // barrier2: drains next-W DMA + next-x loads; frees xs
    if (kc < NCHUNK1 - 1) { xv0 = nx0; xv1 = nx1; xv2 = nx2; xv3 = nx3; }
  }

  // epilogue 1: bias + relu + cvt -> hs (C/D layout: col=l&15, row=(l>>4)*4+j)
#pragma unroll
  for (int n = 0; n < 4; ++n) {
    int col = wc * 64 + n * 16 + l15;
    float bv = biasLds[col];
#pragma unroll
    for (int m = 0; m < 4; ++m)
#pragma unroll
      for (int j = 0; j < 4; ++j) {
        int row = wr * 64 + m * 16 + lg * 4 + j;
        float hv = acc[m][n][j] + bv;
        hs[row][col] = f2bf(fmaxf(hv, 0.f));
      }
  }

#pragma unroll
  for (int m = 0; m < 4; ++m)
#pragma unroll
    for (int n = 0; n < 4; ++n)
#pragma unroll
      for (int j = 0; j < 4; ++j) acc[m][n][j] = 0.f;

  __syncthreads();  // hs ready (W2(0) DMA already drained at last barrier2)

  // ---------------- layer 2: out = h @ W2 + b2 (1 barrier/chunk) ----------------
#pragma unroll
  for (int kc = 0; kc < NCHUNK2; ++kc) {
    if (kc < NCHUNK2 - 1)
      stage_w(w2t + (kc + 1) * 16384, wsl[(kc + 1) & 1], w, l);

    const short* wcur = wsl[kc & 1];
#pragma unroll
    for (int ks = 0; ks < 2; ++ks) {
      const int k8 = ks * 32 + lg * 8;
      short8 a[4], b[4];
#pragma unroll
      for (int m = 0; m < 4; ++m)
        a[m] = *(const short8*)&hs[wr * 64 + m * 16 + l15][kc * 64 + k8];
#pragma unroll
      for (int n = 0; n < 4; ++n) {
        int nn = wc * 64 + n * 16 + l15;
        int blk = (k8 >> 3) ^ (nn & 7);
        b[n] = *(const short8*)&wcur[nn * 64 + blk * 8];
      }
#pragma unroll
      for (int m = 0; m < 4; ++m)
#pragma unroll
        for (int n = 0; n < 4; ++n)
          acc[m][n] = __builtin_amdgcn_mfma_f32_16x16x32_bf16(a[m], b[n], acc[m][n], 0, 0, 0);
    }
    if (kc < NCHUNK2 - 1) __syncthreads();  // drains next-W DMA; no final barrier
  }

  // epilogue 2: bias + store (register-only; 64-B coalesced segments/16 lanes)
#pragma unroll
  for (int n = 0; n < 4; ++n) {
    int col = wc * 64 + n * 16 + l15;
    float bv = biasLds[HID + col];
#pragma unroll
    for (int m = 0; m < 4; ++m) {
      int rbase = r0 + wr * 64 + m * 16 + lg * 4;
#pragma unroll
      for (int j = 0; j < 4; ++j) {
        int r = rbase + j;
        if (r < E_EDGES) out[(size_t)r * HID + col] = acc[m][n][j] + bv;
      }
    }
  }
}

extern "C" void kernel_launch(void* const* d_in, const int* in_sizes, int n_in,
                              void* d_out, int out_size, void* d_ws, size_t ws_size,
                              hipStream_t stream) {
  const float* src = (const float*)d_in[0];
  const float* dst = (const float*)d_in[1];
  const float* edg = (const float*)d_in[2];
  const float* u   = (const float*)d_in[3];
  const int* batch = (const int*)d_in[4];   // harness: integer -> int32
  const float* W1 = (const float*)d_in[5];
  const float* b1 = (const float*)d_in[6];
  const float* W2 = (const float*)d_in[7];
  const float* b2 = (const float*)d_in[8];
  float* out = (float*)d_out;

  short* w1t = (short*)d_ws;                 // 6 tiles * 16384 bf16
  short* w2t = w1t + CAT * HID;              // 4 tiles * 16384 bf16

  int prep_grid = (CAT * HID + HID * HID) / 256;  // 640 (exact)
  prep_weights<<<prep_grid, 256, 0, stream>>>(W1, W2, w1t, w2t);

  int grid = (E_EDGES + BM - 1) / BM;        // 3907
  edge_mlp<<<grid, 512, 0, stream>>>(src, dst, edg, u, batch, b1, b2, w1t, w2t, out);
}

// Round 8
// 1097.100 us; speedup vs baseline: 1.0039x; 1.0039x over previous
//
// Round 8: first measured round (r7: 487µs, PASS, absmax 0.0156).
// Diagnosis: latency/occupancy-bound (Occ 22%, Mfma 14%, HBM 27%; dur == bytes
// at 8.5 GB/s/CU). Fix: 2 blocks/CU — BM 128->64, 256 thr, BK 64->32 so the
// W-dbuf fits: LDS 72KB (xs 5.1K + wsl 32K + hs 33.8K + bias 2K). Structure,
// prefetch depth, swizzle, barrier semantics unchanged (clean attribution).
#include <hip/hip_runtime.h>
#include <hip/hip_bf16.h>

#define E_EDGES 500000
#define V_IN 128
#define E_IN 64
#define U_IN 64
#define NG 512
#define HID 256
#define CAT 384          // 2*V_IN + E_IN + U_IN
#define BM 64
#define BK 32
#define NCHUNK1 12       // 384/32
#define NCHUNK2 8        // 256/32
#define TILE 8192        // HID*BK elements per W tile (16 KB bf16)

typedef short short8 __attribute__((ext_vector_type(8)));
typedef float f32x4 __attribute__((ext_vector_type(4)));

// fp32 -> bf16 round-to-nearest-even
static __device__ __forceinline__ short f2bf(float f) {
  unsigned u = __builtin_bit_cast(unsigned, f);
  u += 0x7fffu + ((u >> 16) & 1u);
  return (short)(u >> 16);
}

static __device__ __forceinline__ void gload_lds16(const void* g, void* l) {
  __builtin_amdgcn_global_load_lds(
      (const __attribute__((address_space(1))) unsigned int*)g,
      (unsigned int __attribute__((address_space(3)))*)l, 16, 0, 0);
}

// 16 KB W tile: 4 waves x 4 KB, LDS dest wave-uniform + lane*16 (rule #21:
// swizzle baked into SOURCE layout by prep).
static __device__ __forceinline__ void stage_w(const short* gsrc, short* lbase,
                                               int w, int l) {
#pragma unroll
  for (int i = 0; i < 4; ++i) {
    int off = (w * 4 + i) * 1024;
    gload_lds16((const char*)gsrc + off + l * 16, (char*)lbase + off);
  }
}

// W1/W2 -> bf16, transposed to [n][k] per 32-k tile, k-block XOR-swizzled (T2):
// element (n, kk) stored at n*32 + ((kk>>3)^(n&3))*8 + (kk&7). Main kernel
// reads with blk = lg ^ (nn&3)  -> bank-uniform ds_read_b128.
__global__ void prep_weights(const float* __restrict__ W1,
                             const float* __restrict__ W2,
                             short* __restrict__ w1t, short* __restrict__ w2t) {
  int idx = blockIdx.x * 256 + threadIdx.x;
  if (idx < CAT * HID) {
    int kc = idx >> 13;            // tile (32 k x 256 n)
    int rem = idx & (TILE - 1);
    int n = rem >> 5, kk = rem & 31;
    int swz = ((((kk >> 3) ^ (n & 3)) << 3) | (kk & 7));
    w1t[kc * TILE + n * 32 + swz] = f2bf(W1[(size_t)(kc * 32 + kk) * HID + n]);
  } else if (idx < CAT * HID + HID * HID) {
    int j = idx - CAT * HID;
    int kc = j >> 13;
    int rem = j & (TILE - 1);
    int n = rem >> 5, kk = rem & 31;
    int swz = ((((kk >> 3) ^ (n & 3)) << 3) | (kk & 7));
    w2t[kc * TILE + n * 32 + swz] = f2bf(W2[(size_t)(kc * 32 + kk) * HID + n]);
  }
}

__global__ __launch_bounds__(256, 2) void edge_mlp(
    const float* __restrict__ src, const float* __restrict__ dst,
    const float* __restrict__ edg, const float* __restrict__ u,
    const int* __restrict__ batch,
    const float* __restrict__ b1, const float* __restrict__ b2,
    const short* __restrict__ w1t, const short* __restrict__ w2t,
    float* __restrict__ out) {
  // LDS: 5120 + 32768 + 33792 + 2048 = 73728 B -> 2 blocks/CU, 8 waves/CU
  __shared__ short xs[BM][40];        // x chunk, +8 pad (bank-uniform reads)
  __shared__ short wsl[2][TILE];      // W tile double-buffer, baked swizzle
  __shared__ short hs[BM][264];       // h, +8 pad
  __shared__ float biasLds[2 * HID];

  const int t = threadIdx.x;
  const int l = t & 63;
  const int wc = t >> 6;              // wave 0..3 = output col quarter
  const int l15 = l & 15, lg = l >> 4;
  const int r0 = blockIdx.x * BM;

  // ---- prologue: kick W1(0) DMA immediately, then x(0) loads ----
  stage_w(w1t, wsl[0], wc, l);

  const int srow = t >> 2;            // x-staging: row = t/4, 8-col piece
  const int cq = (t & 3) << 3;        // float col offset 0/8/16/24
  int gr = r0 + srow;
  if (gr >= E_EDGES) gr = E_EDGES - 1;          // tail clamp (stores guarded)
  int bi = batch[gr];                           // int32 per harness contract
  bi = bi < 0 ? 0 : (bi >= NG ? NG - 1 : bi);   // defensive clamp
  const float* uptr = u + (size_t)bi * U_IN;
  const float* csrc[NCHUNK1] = {
      src + (size_t)gr * V_IN + cq,        src + (size_t)gr * V_IN + 32 + cq,
      src + (size_t)gr * V_IN + 64 + cq,   src + (size_t)gr * V_IN + 96 + cq,
      dst + (size_t)gr * V_IN + cq,        dst + (size_t)gr * V_IN + 32 + cq,
      dst + (size_t)gr * V_IN + 64 + cq,   dst + (size_t)gr * V_IN + 96 + cq,
      edg + (size_t)gr * E_IN + cq,        edg + (size_t)gr * E_IN + 32 + cq,
      uptr + cq,                           uptr + 32 + cq};

  f32x4 xv0, xv1;
  {
    const f32x4* p = (const f32x4*)csrc[0];
    xv0 = p[0]; xv1 = p[1];
  }

  biasLds[t] = b1[t];
  biasLds[t + HID] = b2[t];

  f32x4 acc[4][4];
#pragma unroll
  for (int m = 0; m < 4; ++m)
#pragma unroll
    for (int n = 0; n < 4; ++n)
#pragma unroll
      for (int j = 0; j < 4; ++j) acc[m][n][j] = 0.f;

  // ---------------- layer 1: h = relu(x @ W1 + b1) ----------------
#pragma unroll
  for (int kc = 0; kc < NCHUNK1; ++kc) {
    // write current x chunk (8 floats -> 8 bf16) to LDS
    {
      short8 v;
      v[0] = f2bf(xv0[0]); v[1] = f2bf(xv0[1]); v[2] = f2bf(xv0[2]); v[3] = f2bf(xv0[3]);
      v[4] = f2bf(xv1[0]); v[5] = f2bf(xv1[1]); v[6] = f2bf(xv1[2]); v[7] = f2bf(xv1[3]);
      *(short8*)&xs[srow][cq] = v;
    }
    __syncthreads();  // barrier1: xs ready; W(kc) DMA drained

    // depth-1: issue next W DMA + next x loads; drain overlaps MFMA below
    f32x4 nx0, nx1;
    if (kc < NCHUNK1 - 1) {
      stage_w(w1t + (kc + 1) * TILE, wsl[(kc + 1) & 1], wc, l);
      const f32x4* p = (const f32x4*)csrc[kc + 1];
      nx0 = p[0]; nx1 = p[1];
    } else {
      stage_w(w2t, wsl[0], wc, l);  // W2(0) for layer 2 (parity: 12 even)
    }

    const short* wcur = wsl[kc & 1];
    short8 a[4], b[4];
#pragma unroll
    for (int m = 0; m < 4; ++m)
      a[m] = *(const short8*)&xs[m * 16 + l15][lg * 8];
#pragma unroll
    for (int n = 0; n < 4; ++n) {
      int nn = wc * 64 + n * 16 + l15;
      int blk = lg ^ (nn & 3);
      b[n] = *(const short8*)&wcur[nn * 32 + blk * 8];
    }
#pragma unroll
    for (int m = 0; m < 4; ++m)
#pragma unroll
      for (int n = 0; n < 4; ++n)
        acc[m][n] = __builtin_amdgcn_mfma_f32_16x16x32_bf16(a[m], b[n], acc[m][n], 0, 0, 0);

    __syncthreads();  // barrier2: drains next-W DMA + next-x loads; frees xs
    if (kc < NCHUNK1 - 1) { xv0 = nx0; xv1 = nx1; }
  }

  // epilogue 1: bias + relu + cvt -> hs (C/D layout: col=l&15, row=(l>>4)*4+j)
#pragma unroll
  for (int n = 0; n < 4; ++n) {
    int col = wc * 64 + n * 16 + l15;
    float bv = biasLds[col];
#pragma unroll
    for (int m = 0; m < 4; ++m)
#pragma unroll
      for (int j = 0; j < 4; ++j) {
        int row = m * 16 + lg * 4 + j;
        float hv = acc[m][n][j] + bv;
        hs[row][col] = f2bf(fmaxf(hv, 0.f));
      }
  }

#pragma unroll
  for (int m = 0; m < 4; ++m)
#pragma unroll
    for (int n = 0; n < 4; ++n)
#pragma unroll
      for (int j = 0; j < 4; ++j) acc[m][n][j] = 0.f;

  __syncthreads();  // hs ready (W2(0) DMA already drained at last barrier2)

  // ---------------- layer 2: out = h @ W2 + b2 (1 barrier/chunk) ----------------
#pragma unroll
  for (int kc = 0; kc < NCHUNK2; ++kc) {
    if (kc < NCHUNK2 - 1)
      stage_w(w2t + (kc + 1) * TILE, wsl[(kc + 1) & 1], wc, l);

    const short* wcur = wsl[kc & 1];
    short8 a[4], b[4];
#pragma unroll
    for (int m = 0; m < 4; ++m)
      a[m] = *(const short8*)&hs[m * 16 + l15][kc * 32 + lg * 8];
#pragma unroll
    for (int n = 0; n < 4; ++n) {
      int nn = wc * 64 + n * 16 + l15;
      int blk = lg ^ (nn & 3);
      b[n] = *(const short8*)&wcur[nn * 32 + blk * 8];
    }
#pragma unroll
    for (int m = 0; m < 4; ++m)
#pragma unroll
      for (int n = 0; n < 4; ++n)
        acc[m][n] = __builtin_amdgcn_mfma_f32_16x16x32_bf16(a[m], b[n], acc[m][n], 0, 0, 0);

    if (kc < NCHUNK2 - 1) __syncthreads();  // drains next-W DMA; no final barrier
  }

  // epilogue 2: bias + store (64-B coalesced segments per 16 lanes)
#pragma unroll
  for (int n = 0; n < 4; ++n) {
    int col = wc * 64 + n * 16 + l15;
    float bv = biasLds[HID + col];
#pragma unroll
    for (int m = 0; m < 4; ++m) {
      int rbase = r0 + m * 16 + lg * 4;
#pragma unroll
      for (int j = 0; j < 4; ++j) {
        int r = rbase + j;
        if (r < E_EDGES) out[(size_t)r * HID + col] = acc[m][n][j] + bv;
      }
    }
  }
}

extern "C" void kernel_launch(void* const* d_in, const int* in_sizes, int n_in,
                              void* d_out, int out_size, void* d_ws, size_t ws_size,
                              hipStream_t stream) {
  const float* src = (const float*)d_in[0];
  const float* dst = (const float*)d_in[1];
  const float* edg = (const float*)d_in[2];
  const float* u   = (const float*)d_in[3];
  const int* batch = (const int*)d_in[4];   // harness: integer -> int32
  const float* W1 = (const float*)d_in[5];
  const float* b1 = (const float*)d_in[6];
  const float* W2 = (const float*)d_in[7];
  const float* b2 = (const float*)d_in[8];
  float* out = (float*)d_out;

  short* w1t = (short*)d_ws;                 // 12 tiles * 8192 bf16
  short* w2t = w1t + CAT * HID;              // 8 tiles * 8192 bf16

  int prep_grid = (CAT * HID + HID * HID) / 256;  // 640 (exact)
  prep_weights<<<prep_grid, 256, 0, stream>>>(W1, W2, w1t, w2t);

  int grid = (E_EDGES + BM - 1) / BM;        // 7813
  edge_mlp<<<grid, 256, 0, stream>>>(src, dst, edg, u, batch, b1, b2, w1t, w2t, out);
}